// Round 11
// baseline (304.975 us; speedup 1.0000x reference)
//
#include <hip/hip_runtime.h>
#include <hip/hip_bf16.h>

typedef __attribute__((ext_vector_type(8))) short bf16x8;
typedef __attribute__((ext_vector_type(4))) float f32x4;
typedef __attribute__((ext_vector_type(16))) float f32x16;
typedef __attribute__((ext_vector_type(4))) unsigned short us4;
typedef __attribute__((ext_vector_type(8))) unsigned short us8;
typedef __attribute__((ext_vector_type(4))) unsigned int u32x4;

#define B_  8
#define C_  512
#define CI_ 256
#define N_  4096

__device__ __forceinline__ unsigned short f2b(float f) {
  unsigned u = __float_as_uint(f);
  u += 0x7FFFu + ((u >> 16) & 1u);          // RNE
  return (unsigned short)(u >> 16);
}

__device__ __forceinline__ unsigned pkbf16(float lo, float hi) {
  union { __hip_bfloat162 h2; unsigned u; } cv;
  cv.h2 = __float22bfloat162_rn(make_float2(lo, hi));
  return cv.u;
}

__device__ __forceinline__ f32x4 mfma16(bf16x8 a, bf16x8 b, f32x4 c) {
  return __builtin_amdgcn_mfma_f32_16x16x32_bf16(a, b, c, 0, 0, 0);
}
__device__ __forceinline__ f32x16 mfma32(bf16x8 a, bf16x8 b, f32x16 c) {
  return __builtin_amdgcn_mfma_f32_32x32x16_bf16(a, b, c, 0, 0, 0);
}

__device__ __forceinline__ void gld16(const void* g, void* l) {
  __builtin_amdgcn_global_load_lds(
      (const __attribute__((address_space(1))) unsigned int*)g,
      (__attribute__((address_space(3))) unsigned int*)l, 16, 0, 0);
}

// ---------------------------------------------------------------- fold BN
// catW = [thW; phW; gW] (768 x 512), bCat = [bTh; bPh; bG]
__global__ void fold_kernel(
  const float* __restrict__ thw, const float* __restrict__ thb,
  const float* __restrict__ thg, const float* __restrict__ thbb,
  const float* __restrict__ thm, const float* __restrict__ thv,
  const float* __restrict__ phw, const float* __restrict__ phb,
  const float* __restrict__ phg, const float* __restrict__ phbb,
  const float* __restrict__ phm, const float* __restrict__ phv,
  const float* __restrict__ gw,  const float* __restrict__ gb,
  const float* __restrict__ wzw, const float* __restrict__ wzb,
  const float* __restrict__ wzg, const float* __restrict__ wzbb,
  const float* __restrict__ wzm, const float* __restrict__ wzv,
  unsigned short* __restrict__ catW, unsigned short* __restrict__ wzW,
  float* __restrict__ bCat, float* __restrict__ bWz)
{
  int i = blockIdx.x * 256 + threadIdx.x;
  const int WSZ = CI_ * C_;  // 131072
  if (i < WSZ) { int o = i >> 9; catW[i] = f2b(thw[i] * (thg[o] * rsqrtf(thv[o] + 1e-5f))); return; }
  i -= WSZ;
  if (i < WSZ) { int o = i >> 9; catW[WSZ + i] = f2b(phw[i] * (phg[o] * rsqrtf(phv[o] + 1e-5f))); return; }
  i -= WSZ;
  if (i < WSZ) { catW[2 * WSZ + i] = f2b(gw[i]); return; }
  i -= WSZ;
  if (i < WSZ) { int o = i >> 8; wzW[i] = f2b(wzw[i] * (wzg[o] * rsqrtf(wzv[o] + 1e-5f))); return; }
  i -= WSZ;
  if (i < CI_) { float s = thg[i] * rsqrtf(thv[i] + 1e-5f); bCat[i] = (thb[i] - thm[i]) * s + thbb[i]; return; }
  i -= CI_;
  if (i < CI_) { float s = phg[i] * rsqrtf(phv[i] + 1e-5f); bCat[256 + i] = (phb[i] - phm[i]) * s + phbb[i]; return; }
  i -= CI_;
  if (i < CI_) { bCat[512 + i] = gb[i]; return; }
  i -= CI_;
  if (i < C_)  { float s = wzg[i] * rsqrtf(wzv[i] + 1e-5f); bWz[i] = (wzb[i] - wzm[i]) * s + wzbb[i]; return; }
}

// ------------------------------------------- x [b][c][n] f32 -> xbT [b][n][c] bf16
__global__ __launch_bounds__(256) void transpose_cast(
  const float* __restrict__ x, unsigned short* __restrict__ xT)
{
  __shared__ float tl[64][68];
  const int b = blockIdx.z, c0 = blockIdx.y * 64, n0 = blockIdx.x * 64;
  const int t = threadIdx.x;
  const int r = t >> 2, q = (t & 3) * 16;
  const float* src = x + ((size_t)(b * C_ + c0 + r)) * N_ + n0 + q;
#pragma unroll
  for (int i = 0; i < 4; i++)
    *(f32x4*)&tl[r][q + i * 4] = *(const f32x4*)(src + i * 4);
  __syncthreads();
  unsigned short* dst = xT + ((size_t)(b * N_ + n0 + r)) * C_ + c0 + q;
  us8 o0, o1;
#pragma unroll
  for (int i = 0; i < 8; i++) o0[i] = f2b(tl[q + i][r]);
#pragma unroll
  for (int i = 0; i < 8; i++) o1[i] = f2b(tl[q + 8 + i][r]);
  *(us8*)dst = o0;
  *(us8*)(dst + 8) = o1;
}

// --------------------------------------------- merged projection GEMM:
// A = catW [768][512]; B = xbT [b][n][512]; m0<512 -> thph [b][n][512] bf16;
// m0>=512 -> gxb [b][ci][n] bf16. 128x128 tile, gld_lds staging, dbuf.
__global__ __launch_bounds__(256, 2) void gemm_proj(
  const unsigned short* __restrict__ A,
  const unsigned short* __restrict__ Bm,
  const float* __restrict__ bias,
  unsigned short* __restrict__ thph,
  unsigned short* __restrict__ gxb)
{
  __shared__ __align__(16) unsigned short Al[2][128][64];
  __shared__ __align__(16) unsigned short Bl[2][128][64];
  const int b = blockIdx.z;
  const int m0 = blockIdx.y * 128;
  const int n0 = blockIdx.x * 128;
  const int t = threadIdx.x;
  const int w = t >> 6, l = t & 63, l15 = l & 15, g = l >> 4;
  const int wm = w >> 1, wn = w & 1;
  const int eg = l15 & 7;
  const unsigned short* Bb = Bm + (size_t)b * N_ * 512;
  f32x4 acc[4][4];
#pragma unroll
  for (int i = 0; i < 4; i++)
#pragma unroll
    for (int j = 0; j < 4; j++) acc[i][j] = (f32x4){0.f, 0.f, 0.f, 0.f};

  int aoff[4], boff[4];
#pragma unroll
  for (int i = 0; i < 4; i++) {
    int j = w * 4 + i;
    int row = j * 8 + (l >> 3);
    int sw = ((l & 7) ^ (l >> 3)) * 8;
    aoff[i] = (m0 + row) * 512 + sw;
    boff[i] = (n0 + row) * 512 + sw;
  }

#define GSTAGE(bufv, k0v) do { \
    _Pragma("unroll") \
    for (int i_ = 0; i_ < 4; i_++) { \
      gld16(A  + aoff[i_] + (k0v), (unsigned char*)&Al[bufv][0][0] + (w * 4 + i_) * 1024); \
      gld16(Bb + boff[i_] + (k0v), (unsigned char*)&Bl[bufv][0][0] + (w * 4 + i_) * 1024); \
    } \
  } while (0)

  GSTAGE(0, 0);
  __syncthreads();
  for (int kk = 0; kk < 8; kk++) {
    if (kk + 1 < 8) GSTAGE((kk + 1) & 1, (kk + 1) * 64);
    const int cb = kk & 1;
#pragma unroll
    for (int ks = 0; ks < 2; ks++) {
      bf16x8 af[4], bfr[4];
#pragma unroll
      for (int i = 0; i < 4; i++)
        af[i]  = *(const bf16x8*)&Al[cb][wm * 64 + i * 16 + l15][((ks * 4 + g) ^ eg) * 8];
#pragma unroll
      for (int j = 0; j < 4; j++)
        bfr[j] = *(const bf16x8*)&Bl[cb][wn * 64 + j * 16 + l15][((ks * 4 + g) ^ eg) * 8];
#pragma unroll
      for (int i = 0; i < 4; i++)
#pragma unroll
        for (int j = 0; j < 4; j++)
          acc[i][j] = mfma16(af[i], bfr[j], acc[i][j]);
    }
    __syncthreads();
  }

#pragma unroll
  for (int i = 0; i < 4; i++) {
    int mrow = m0 + wm * 64 + i * 16 + 4 * g;
    f32x4 b4 = *(const f32x4*)&bias[mrow];
#pragma unroll
    for (int j = 0; j < 4; j++) {
      int n = n0 + wn * 64 + j * 16 + l15;
      f32x4 v = acc[i][j];
      v += b4;
      if (m0 < 512) {
        us4 pk = { f2b(v[0]), f2b(v[1]), f2b(v[2]), f2b(v[3]) };
        *(us4*)(thph + ((size_t)b * N_ + n) * 512 + mrow) = pk;
      } else {
        unsigned short* o = gxb + ((size_t)b * CI_ + (mrow - 512)) * (size_t)N_ + n;
#pragma unroll
        for (int jj = 0; jj < 4; jj++) o[(size_t)jj * N_] = f2b(v[jj]);
      }
    }
  }
#undef GSTAGE
}

// ------------------------------------------------ BT GEMM (wz), 128x128 tile
__global__ __launch_bounds__(256, 2) void gemm_wz(
  const unsigned short* __restrict__ A,
  const unsigned short* __restrict__ Bm,
  const float* __restrict__ bias,
  const float* __restrict__ resid,
  float* __restrict__ outp)
{
  __shared__ __align__(16) unsigned short Al[2][128][64];
  __shared__ __align__(16) unsigned short Bl[2][128][64];
  const int Mdim = 512, Ndim = N_, Kdim = 256;
  const int b = blockIdx.z;
  const int m0 = blockIdx.y * 128;
  const int n0 = blockIdx.x * 128;
  const int t = threadIdx.x;
  const int w = t >> 6, l = t & 63, l15 = l & 15, g = l >> 4;
  const int wm = w >> 1, wn = w & 1;
  const int eg = l15 & 7;
  const unsigned short* Bb = Bm + (size_t)b * Ndim * Kdim;
  f32x4 acc[4][4];
#pragma unroll
  for (int i = 0; i < 4; i++)
#pragma unroll
    for (int j = 0; j < 4; j++) acc[i][j] = (f32x4){0.f, 0.f, 0.f, 0.f};

  int aoff[4], boff[4];
#pragma unroll
  for (int i = 0; i < 4; i++) {
    int j = w * 4 + i;
    int row = j * 8 + (l >> 3);
    int sw = ((l & 7) ^ (l >> 3)) * 8;
    aoff[i] = (m0 + row) * Kdim + sw;
    boff[i] = (n0 + row) * Kdim + sw;
  }

#define GSTAGE(bufv, k0v) do { \
    _Pragma("unroll") \
    for (int i_ = 0; i_ < 4; i_++) { \
      gld16(A  + aoff[i_] + (k0v), (unsigned char*)&Al[bufv][0][0] + (w * 4 + i_) * 1024); \
      gld16(Bb + boff[i_] + (k0v), (unsigned char*)&Bl[bufv][0][0] + (w * 4 + i_) * 1024); \
    } \
  } while (0)

  GSTAGE(0, 0);
  __syncthreads();
  for (int kk = 0; kk < 4; kk++) {
    if (kk + 1 < 4) GSTAGE((kk + 1) & 1, (kk + 1) * 64);
    const int cb = kk & 1;
#pragma unroll
    for (int ks = 0; ks < 2; ks++) {
      bf16x8 af[4], bfr[4];
#pragma unroll
      for (int i = 0; i < 4; i++)
        af[i]  = *(const bf16x8*)&Al[cb][wm * 64 + i * 16 + l15][((ks * 4 + g) ^ eg) * 8];
#pragma unroll
      for (int j = 0; j < 4; j++)
        bfr[j] = *(const bf16x8*)&Bl[cb][wn * 64 + j * 16 + l15][((ks * 4 + g) ^ eg) * 8];
#pragma unroll
      for (int i = 0; i < 4; i++)
#pragma unroll
        for (int j = 0; j < 4; j++)
          acc[i][j] = mfma16(af[i], bfr[j], acc[i][j]);
    }
    __syncthreads();
  }

#pragma unroll
  for (int i = 0; i < 4; i++) {
    int mrow = m0 + wm * 64 + i * 16 + 4 * g;
    f32x4 b4 = *(const f32x4*)&bias[mrow];
#pragma unroll
    for (int j = 0; j < 4; j++) {
      int n = n0 + wn * 64 + j * 16 + l15;
      f32x4 v = acc[i][j];
      v += b4;
      size_t base = ((size_t)b * Mdim + mrow) * (size_t)Ndim + n;
#pragma unroll
      for (int jj = 0; jj < 4; jj++)
        outp[base + (size_t)jj * Ndim] = v[jj] + resid[base + (size_t)jj * Ndim];
    }
  }
#undef GSTAGE
}

// -------------------------------------------------------- flash attention
// R8-exact structure (best measured: 214us): 512 thr, 8 waves (qt=w&3,
// mh=w>>2), 64-row K/V tiles double-buffered (128KB), stage-ahead + single
// __syncthreads per iter. Q/K read from fused thph [b][n][512] (ph at +256).
__global__ __launch_bounds__(512, 2) void attn_kernel(
  const unsigned short* __restrict__ thph,
  const unsigned short* __restrict__ gx,
  unsigned short* __restrict__ yT)
{
  __shared__ __align__(16) unsigned char lds[135168]; // 128K KV dbuf + 4K M/L
  const int t = threadIdx.x;
  const int w = t >> 6, l = t & 63, l31 = l & 31, h = l >> 5;
  const int qt = w & 3, mh = w >> 2;
  const int e7 = l31 & 7;
  const int id = blockIdx.x;
  const int b = id & 7;               // XCD-swizzle: one batch per XCD
  const int n0 = (id >> 3) * 128;
  const unsigned short* tpB = thph + (size_t)b * N_ * 512;
  const unsigned short* gxB = gx  + (size_t)b * CI_ * N_;

  // staging source offsets; content swizzle: LDS(row,g) = global(row, g ^ rowbits)
  const int kq = l >> 5, kc = l & 31;
  int koff[4];
#pragma unroll
  for (int i = 0; i < 4; i++) {
    int row = w * 8 + 2 * i + kq;                // K tile row (64 rows)
    koff[i] = row * 512 + 256 + ((kc ^ (row & 7)) * 8);   // ph cols 256..511
  }
  const int vq = l >> 3, vc = l & 7;
  int voff[4];
#pragma unroll
  for (int i = 0; i < 4; i++) {
    int ci = w * 32 + i * 8 + vq;                // V row (256 ci rows)
    voff[i] = ci * 4096 + ((vc ^ vq) * 8);
  }

#define STAGE(bufv, m0v) do { \
    const unsigned short* kg_ = tpB + (size_t)(m0v) * 512; \
    const unsigned short* vg_ = gxB + (m0v); \
    unsigned base_ = (unsigned)(bufv) * 65536u + (unsigned)w * 4096u; \
    _Pragma("unroll") \
    for (int i_ = 0; i_ < 4; i_++) \
      gld16(kg_ + koff[i_], lds + base_ + i_ * 1024); \
    _Pragma("unroll") \
    for (int i_ = 0; i_ < 4; i_++) \
      gld16(vg_ + voff[i_], lds + base_ + 32768u + i_ * 1024); \
  } while (0)

  // Q fragments (B-operand): lane holds Q[n = l31][ci = ks*16 + h*8 + j]
  bf16x8 q[16];
  {
    const unsigned short* qp = tpB + (size_t)(n0 + qt * 32 + l31) * 512 + h * 8;
#pragma unroll
    for (int ks = 0; ks < 16; ks++) q[ks] = *(const bf16x8*)(qp + ks * 16);
  }

  f32x16 acc[8];
#pragma unroll
  for (int i = 0; i < 8; i++)
#pragma unroll
    for (int r = 0; r < 16; r++) acc[i][r] = 0.f;
  float M = -1e30f, L = 0.f;
  const float kS = 0.0625f * 1.44269504f;   // Ci^-0.5 * log2(e)

  STAGE(0, 0);
  __syncthreads();
  int cur = 0;

  for (int tt = 0; tt < 64; tt++) {
    const int m0 = tt * 64;
    if (tt < 63) STAGE(cur ^ 1, m0 + 64);
    const unsigned char* kb = lds + cur * 65536;
    const unsigned char* vb = kb + 32768;

    // S = K * Q over this wave's 32-m half: D[mloc=(r&3)+8*(r>>2)+4h][n=l31]
    f32x16 S;
#pragma unroll
    for (int r = 0; r < 16; r++) S[r] = 0.f;
#pragma unroll
    for (int ks = 0; ks < 16; ks++) {
      bf16x8 kf = *(const bf16x8*)(kb + (mh * 32 + l31) * 512 + ((((ks * 2 + h)) ^ e7) << 4));
      S = mfma32(kf, q[ks], S);
    }

    // online softmax (per-lane col n = l31), log2 domain
    float pm = S[0];
#pragma unroll
    for (int r = 1; r < 16; r++) pm = fmaxf(pm, S[r]);
    pm *= kS;
    pm = fmaxf(pm, __shfl_xor(pm, 32));
    int dfr = __all(pm <= M + 8.0f);          // defer-max (T13)
    if (!dfr) {
      float nm = fmaxf(M, pm);
      float rs = exp2f(M - nm);
      M = nm; L *= rs;
#pragma unroll
      for (int r = 0; r < 16; r++) {
        float rr = __shfl(rs, h * 32 + ((r & 3) + 8 * (r >> 2) + 4 * h));
#pragma unroll
        for (int c = 0; c < 8; c++) acc[c][r] *= rr;
      }
    }
    float p[16];
    float rsum = 0.f;
#pragma unroll
    for (int r = 0; r < 16; r++) {
      p[r] = exp2f(S[r] * kS - M);
      rsum += p[r];
    }
    rsum += __shfl_xor(rsum, 32);
    L += rsum;

    // pack P: pk[qq] covers mloc pair base = 2*(qq&1) + 8*(qq>>1) + 4h
    unsigned pk[8];
#pragma unroll
    for (int qq = 0; qq < 8; qq++)
      pk[qq] = pkbf16(p[2 * qq], p[2 * qq + 1]);

    // PV: A-frag lane l31 = n, k = mloc; words via shfl_xor(32) + select
#pragma unroll
    for (int ks = 0; ks < 2; ks++) {
      unsigned s00 = pk[ks * 4 + 0], s10 = pk[ks * 4 + 2];
      unsigned s01 = pk[ks * 4 + 1], s11 = pk[ks * 4 + 3];
      unsigned own0 = h ? s10 : s00;
      unsigned snd0 = h ? s00 : s10;
      unsigned own1 = h ? s11 : s01;
      unsigned snd1 = h ? s01 : s11;
      unsigned sw0 = (unsigned)__shfl_xor((int)snd0, 32);
      unsigned sw1 = (unsigned)__shfl_xor((int)snd1, 32);
      u32x4 pv;
      pv[0] = h ? sw0 : own0;
      pv[1] = h ? sw1 : own1;
      pv[2] = h ? own0 : sw0;
      pv[3] = h ? own1 : sw1;
      bf16x8 pa = *(bf16x8*)&pv;
      const int gidx = mh * 4 + ks * 2 + h;   // V granule (0..7)
#pragma unroll
      for (int cit = 0; cit < 8; cit++) {
        bf16x8 vf = *(const bf16x8*)(vb + (cit * 32 + l31) * 128 + ((gidx ^ e7) << 4));
        acc[cit] = mfma32(pa, vf, acc[cit]);
      }
    }
    __syncthreads();
    cur ^= 1;
  }

  // ---- pair-merge (qt, mh=0) <- (qt, mh=1) through LDS
  float* MB = (float*)(lds + 131072);          // [2][4][64]
  float* LB = (float*)(lds + 131072 + 2048);   // [2][4][64]
  MB[mh * 256 + qt * 64 + l] = M;
  LB[mh * 256 + qt * 64 + l] = L;
  float* ab = (float*)lds + qt * 8192 + l;     // 32KB region per qt
  if (mh) {
#pragma unroll
    for (int cit = 0; cit < 8; cit++)
#pragma unroll
      for (int r = 0; r < 16; r++)
        ab[(cit * 16 + r) * 64] = acc[cit][r];
  }
  __syncthreads();
  if (!mh) {
    unsigned short* yB = yT + (size_t)b * N_ * CI_;
#pragma unroll
    for (int r = 0; r < 16; r++) {
      int nl = (r & 3) + 8 * (r >> 2) + 4 * h;
      int li = qt * 64 + h * 32 + nl;
      float M1 = MB[li], L1 = LB[li];
      float M2 = MB[256 + li], L2 = LB[256 + li];
      float Mf = fmaxf(M1, M2);
      float s1 = exp2f(M1 - Mf), s2 = exp2f(M2 - Mf);
      float invf = 1.0f / (L1 * s1 + L2 * s2);
      s1 *= invf; s2 *= invf;
      int n = n0 + qt * 32 + nl;
#pragma unroll
      for (int cit = 0; cit < 8; cit++) {
        float v = acc[cit][r] * s1 + ab[(cit * 16 + r) * 64] * s2;
        yB[(size_t)n * CI_ + cit * 32 + l31] = f2b(v);
      }
    }
  }
#undef STAGE
}

// ---------------------------------------------------------------- host
extern "C" void kernel_launch(void* const* d_in, const int* in_sizes, int n_in,
                              void* d_out, int out_size, void* d_ws, size_t ws_size,
                              hipStream_t stream)
{
  const float* x    = (const float*)d_in[0];
  const float* thw  = (const float*)d_in[1];
  const float* thb  = (const float*)d_in[2];
  const float* thg  = (const float*)d_in[3];
  const float* thbb = (const float*)d_in[4];
  const float* thm  = (const float*)d_in[5];
  const float* thv  = (const float*)d_in[6];
  const float* phw  = (const float*)d_in[7];
  const float* phb  = (const float*)d_in[8];
  const float* phg  = (const float*)d_in[9];
  const float* phbb = (const float*)d_in[10];
  const float* phm  = (const float*)d_in[11];
  const float* phv  = (const float*)d_in[12];
  const float* gw   = (const float*)d_in[13];
  const float* gb   = (const float*)d_in[14];
  const float* wzw  = (const float*)d_in[15];
  const float* wzb  = (const float*)d_in[16];
  const float* wzg  = (const float*)d_in[17];
  const float* wzbb = (const float*)d_in[18];
  const float* wzm  = (const float*)d_in[19];
  const float* wzv  = (const float*)d_in[20];

  char* ws = (char*)d_ws;
  unsigned short* xbT  = (unsigned short*)(ws);                    // 32 MB [b][n][512]
  unsigned short* thph = (unsigned short*)(ws + 33554432ull);      // 32 MB [b][n][512] th|ph
  unsigned short* gxb  = (unsigned short*)(ws + 67108864ull);      // 16 MB [b][ci][n]
  unsigned short* yT   = (unsigned short*)(ws + 83886080ull);      // 16 MB [b][n][ci]
  unsigned short* catW = (unsigned short*)(ws + 100663296ull);     // 768x512 bf16
  unsigned short* wzW  = (unsigned short*)(ws + 101449728ull);     // 512x256 bf16
  float* bCat = (float*)(ws + 101711872ull);                       // 768 f32
  float* bWz  = (float*)(ws + 101714944ull);                       // 512 f32

  fold_kernel<<<2053, 256, 0, stream>>>(
      thw, thb, thg, thbb, thm, thv,
      phw, phb, phg, phbb, phm, phv,
      gw, gb, wzw, wzb, wzg, wzbb, wzm, wzv,
      catW, wzW, bCat, bWz);

  transpose_cast<<<dim3(64, 8, 8), 256, 0, stream>>>(x, xbT);

  gemm_proj<<<dim3(32, 6, 8), 256, 0, stream>>>(catW, xbT, bCat, thph, gxb);

  attn_kernel<<<dim3(256), 512, 0, stream>>>(thph, gxb, yT);

  gemm_wz<<<dim3(32, 4, 8), 256, 0, stream>>>(wzW, yT, bWz, x, (float*)d_out);
}

// Round 12
// 279.238 us; speedup vs baseline: 1.0922x; 1.0922x over previous
//
#include <hip/hip_runtime.h>
#include <hip/hip_bf16.h>

typedef __attribute__((ext_vector_type(8))) short bf16x8;
typedef __attribute__((ext_vector_type(4))) float f32x4;
typedef __attribute__((ext_vector_type(16))) float f32x16;
typedef __attribute__((ext_vector_type(4))) unsigned short us4;
typedef __attribute__((ext_vector_type(8))) unsigned short us8;
typedef __attribute__((ext_vector_type(4))) unsigned int u32x4;

#define B_  8
#define C_  512
#define CI_ 256
#define N_  4096

__device__ __forceinline__ unsigned short f2b(float f) {
  unsigned u = __float_as_uint(f);
  u += 0x7FFFu + ((u >> 16) & 1u);          // RNE
  return (unsigned short)(u >> 16);
}

__device__ __forceinline__ unsigned pkbf16(float lo, float hi) {
  union { __hip_bfloat162 h2; unsigned u; } cv;
  cv.h2 = __float22bfloat162_rn(make_float2(lo, hi));
  return cv.u;
}

__device__ __forceinline__ f32x4 mfma16(bf16x8 a, bf16x8 b, f32x4 c) {
  return __builtin_amdgcn_mfma_f32_16x16x32_bf16(a, b, c, 0, 0, 0);
}
__device__ __forceinline__ f32x16 mfma32(bf16x8 a, bf16x8 b, f32x16 c) {
  return __builtin_amdgcn_mfma_f32_32x32x16_bf16(a, b, c, 0, 0, 0);
}

__device__ __forceinline__ void gld16(const void* g, void* l) {
  __builtin_amdgcn_global_load_lds(
      (const __attribute__((address_space(1))) unsigned int*)g,
      (__attribute__((address_space(3))) unsigned int*)l, 16, 0, 0);
}

// ---------------------------------------------------------------- fold BN
// catW = [thW; phW; gW] (768 x 512), bCat = [bTh; bPh; bG]
__global__ void fold_kernel(
  const float* __restrict__ thw, const float* __restrict__ thb,
  const float* __restrict__ thg, const float* __restrict__ thbb,
  const float* __restrict__ thm, const float* __restrict__ thv,
  const float* __restrict__ phw, const float* __restrict__ phb,
  const float* __restrict__ phg, const float* __restrict__ phbb,
  const float* __restrict__ phm, const float* __restrict__ phv,
  const float* __restrict__ gw,  const float* __restrict__ gb,
  const float* __restrict__ wzw, const float* __restrict__ wzb,
  const float* __restrict__ wzg, const float* __restrict__ wzbb,
  const float* __restrict__ wzm, const float* __restrict__ wzv,
  unsigned short* __restrict__ catW, unsigned short* __restrict__ wzW,
  float* __restrict__ bCat, float* __restrict__ bWz)
{
  int i = blockIdx.x * 256 + threadIdx.x;
  const int WSZ = CI_ * C_;  // 131072
  if (i < WSZ) { int o = i >> 9; catW[i] = f2b(thw[i] * (thg[o] * rsqrtf(thv[o] + 1e-5f))); return; }
  i -= WSZ;
  if (i < WSZ) { int o = i >> 9; catW[WSZ + i] = f2b(phw[i] * (phg[o] * rsqrtf(phv[o] + 1e-5f))); return; }
  i -= WSZ;
  if (i < WSZ) { catW[2 * WSZ + i] = f2b(gw[i]); return; }
  i -= WSZ;
  if (i < WSZ) { int o = i >> 8; wzW[i] = f2b(wzw[i] * (wzg[o] * rsqrtf(wzv[o] + 1e-5f))); return; }
  i -= WSZ;
  if (i < CI_) { float s = thg[i] * rsqrtf(thv[i] + 1e-5f); bCat[i] = (thb[i] - thm[i]) * s + thbb[i]; return; }
  i -= CI_;
  if (i < CI_) { float s = phg[i] * rsqrtf(phv[i] + 1e-5f); bCat[256 + i] = (phb[i] - phm[i]) * s + phbb[i]; return; }
  i -= CI_;
  if (i < CI_) { bCat[512 + i] = gb[i]; return; }
  i -= CI_;
  if (i < C_)  { float s = wzg[i] * rsqrtf(wzv[i] + 1e-5f); bWz[i] = (wzb[i] - wzm[i]) * s + wzbb[i]; return; }
}

// ------------------------------------------- x [b][c][n] f32 -> xbT [b][n][c] bf16
__global__ __launch_bounds__(256) void transpose_cast(
  const float* __restrict__ x, unsigned short* __restrict__ xT)
{
  __shared__ float tl[64][68];
  const int b = blockIdx.z, c0 = blockIdx.y * 64, n0 = blockIdx.x * 64;
  const int t = threadIdx.x;
  const int r = t >> 2, q = (t & 3) * 16;
  const float* src = x + ((size_t)(b * C_ + c0 + r)) * N_ + n0 + q;
#pragma unroll
  for (int i = 0; i < 4; i++)
    *(f32x4*)&tl[r][q + i * 4] = *(const f32x4*)(src + i * 4);
  __syncthreads();
  unsigned short* dst = xT + ((size_t)(b * N_ + n0 + r)) * C_ + c0 + q;
  us8 o0, o1;
#pragma unroll
  for (int i = 0; i < 8; i++) o0[i] = f2b(tl[q + i][r]);
#pragma unroll
  for (int i = 0; i < 8; i++) o1[i] = f2b(tl[q + 8 + i][r]);
  *(us8*)dst = o0;
  *(us8*)(dst + 8) = o1;
}

// --------------------------------------------- merged projection GEMM:
// A = catW [768][512]; B = xbT [b][n][512].
// m0<256 -> thT [b][n][256]; m0<512 -> phT [b][n][256]; else gxb [b][ci][n].
__global__ __launch_bounds__(256, 2) void gemm_proj(
  const unsigned short* __restrict__ A,
  const unsigned short* __restrict__ Bm,
  const float* __restrict__ bias,
  unsigned short* __restrict__ thT,
  unsigned short* __restrict__ phT,
  unsigned short* __restrict__ gxb)
{
  __shared__ __align__(16) unsigned short Al[2][128][64];
  __shared__ __align__(16) unsigned short Bl[2][128][64];
  const int b = blockIdx.z;
  const int m0 = blockIdx.y * 128;
  const int n0 = blockIdx.x * 128;
  const int t = threadIdx.x;
  const int w = t >> 6, l = t & 63, l15 = l & 15, g = l >> 4;
  const int wm = w >> 1, wn = w & 1;
  const int eg = l15 & 7;
  const unsigned short* Bb = Bm + (size_t)b * N_ * 512;
  f32x4 acc[4][4];
#pragma unroll
  for (int i = 0; i < 4; i++)
#pragma unroll
    for (int j = 0; j < 4; j++) acc[i][j] = (f32x4){0.f, 0.f, 0.f, 0.f};

  int aoff[4], boff[4];
#pragma unroll
  for (int i = 0; i < 4; i++) {
    int j = w * 4 + i;
    int row = j * 8 + (l >> 3);
    int sw = ((l & 7) ^ (l >> 3)) * 8;
    aoff[i] = (m0 + row) * 512 + sw;
    boff[i] = (n0 + row) * 512 + sw;
  }

#define GSTAGE(bufv, k0v) do { \
    _Pragma("unroll") \
    for (int i_ = 0; i_ < 4; i_++) { \
      gld16(A  + aoff[i_] + (k0v), (unsigned char*)&Al[bufv][0][0] + (w * 4 + i_) * 1024); \
      gld16(Bb + boff[i_] + (k0v), (unsigned char*)&Bl[bufv][0][0] + (w * 4 + i_) * 1024); \
    } \
  } while (0)

  GSTAGE(0, 0);
  __syncthreads();
  for (int kk = 0; kk < 8; kk++) {
    if (kk + 1 < 8) GSTAGE((kk + 1) & 1, (kk + 1) * 64);
    const int cb = kk & 1;
#pragma unroll
    for (int ks = 0; ks < 2; ks++) {
      bf16x8 af[4], bfr[4];
#pragma unroll
      for (int i = 0; i < 4; i++)
        af[i]  = *(const bf16x8*)&Al[cb][wm * 64 + i * 16 + l15][((ks * 4 + g) ^ eg) * 8];
#pragma unroll
      for (int j = 0; j < 4; j++)
        bfr[j] = *(const bf16x8*)&Bl[cb][wn * 64 + j * 16 + l15][((ks * 4 + g) ^ eg) * 8];
#pragma unroll
      for (int i = 0; i < 4; i++)
#pragma unroll
        for (int j = 0; j < 4; j++)
          acc[i][j] = mfma16(af[i], bfr[j], acc[i][j]);
    }
    __syncthreads();
  }

#pragma unroll
  for (int i = 0; i < 4; i++) {
    int mrow = m0 + wm * 64 + i * 16 + 4 * g;
    f32x4 b4 = *(const f32x4*)&bias[mrow];
#pragma unroll
    for (int j = 0; j < 4; j++) {
      int n = n0 + wn * 64 + j * 16 + l15;
      f32x4 v = acc[i][j];
      v += b4;
      if (mrow < 256) {
        us4 pk = { f2b(v[0]), f2b(v[1]), f2b(v[2]), f2b(v[3]) };
        *(us4*)(thT + ((size_t)b * N_ + n) * 256 + mrow) = pk;
      } else if (mrow < 512) {
        us4 pk = { f2b(v[0]), f2b(v[1]), f2b(v[2]), f2b(v[3]) };
        *(us4*)(phT + ((size_t)b * N_ + n) * 256 + (mrow - 256)) = pk;
      } else {
        unsigned short* o = gxb + ((size_t)b * CI_ + (mrow - 512)) * (size_t)N_ + n;
#pragma unroll
        for (int jj = 0; jj < 4; jj++) o[(size_t)jj * N_] = f2b(v[jj]);
      }
    }
  }
#undef GSTAGE
}

// ------------------------------------------------ BT GEMM (wz), 128x128 tile
__global__ __launch_bounds__(256, 2) void gemm_wz(
  const unsigned short* __restrict__ A,
  const unsigned short* __restrict__ Bm,
  const float* __restrict__ bias,
  const float* __restrict__ resid,
  float* __restrict__ outp)
{
  __shared__ __align__(16) unsigned short Al[2][128][64];
  __shared__ __align__(16) unsigned short Bl[2][128][64];
  const int Mdim = 512, Ndim = N_, Kdim = 256;
  const int b = blockIdx.z;
  const int m0 = blockIdx.y * 128;
  const int n0 = blockIdx.x * 128;
  const int t = threadIdx.x;
  const int w = t >> 6, l = t & 63, l15 = l & 15, g = l >> 4;
  const int wm = w >> 1, wn = w & 1;
  const int eg = l15 & 7;
  const unsigned short* Bb = Bm + (size_t)b * Ndim * Kdim;
  f32x4 acc[4][4];
#pragma unroll
  for (int i = 0; i < 4; i++)
#pragma unroll
    for (int j = 0; j < 4; j++) acc[i][j] = (f32x4){0.f, 0.f, 0.f, 0.f};

  int aoff[4], boff[4];
#pragma unroll
  for (int i = 0; i < 4; i++) {
    int j = w * 4 + i;
    int row = j * 8 + (l >> 3);
    int sw = ((l & 7) ^ (l >> 3)) * 8;
    aoff[i] = (m0 + row) * Kdim + sw;
    boff[i] = (n0 + row) * Kdim + sw;
  }

#define GSTAGE(bufv, k0v) do { \
    _Pragma("unroll") \
    for (int i_ = 0; i_ < 4; i_++) { \
      gld16(A  + aoff[i_] + (k0v), (unsigned char*)&Al[bufv][0][0] + (w * 4 + i_) * 1024); \
      gld16(Bb + boff[i_] + (k0v), (unsigned char*)&Bl[bufv][0][0] + (w * 4 + i_) * 1024); \
    } \
  } while (0)

  GSTAGE(0, 0);
  __syncthreads();
  for (int kk = 0; kk < 4; kk++) {
    if (kk + 1 < 4) GSTAGE((kk + 1) & 1, (kk + 1) * 64);
    const int cb = kk & 1;
#pragma unroll
    for (int ks = 0; ks < 2; ks++) {
      bf16x8 af[4], bfr[4];
#pragma unroll
      for (int i = 0; i < 4; i++)
        af[i]  = *(const bf16x8*)&Al[cb][wm * 64 + i * 16 + l15][((ks * 4 + g) ^ eg) * 8];
#pragma unroll
      for (int j = 0; j < 4; j++)
        bfr[j] = *(const bf16x8*)&Bl[cb][wn * 64 + j * 16 + l15][((ks * 4 + g) ^ eg) * 8];
#pragma unroll
      for (int i = 0; i < 4; i++)
#pragma unroll
        for (int j = 0; j < 4; j++)
          acc[i][j] = mfma16(af[i], bfr[j], acc[i][j]);
    }
    __syncthreads();
  }

#pragma unroll
  for (int i = 0; i < 4; i++) {
    int mrow = m0 + wm * 64 + i * 16 + 4 * g;
    f32x4 b4 = *(const f32x4*)&bias[mrow];
#pragma unroll
    for (int j = 0; j < 4; j++) {
      int n = n0 + wn * 64 + j * 16 + l15;
      f32x4 v = acc[i][j];
      v += b4;
      size_t base = ((size_t)b * Mdim + mrow) * (size_t)Ndim + n;
#pragma unroll
      for (int jj = 0; jj < 4; jj++)
        outp[base + (size_t)jj * Ndim] = v[jj] + resid[base + (size_t)jj * Ndim];
    }
  }
#undef GSTAGE
}

// -------------------------------------------------------- flash attention
// R8-exact (best measured: 214us): 512 thr, 8 waves (qt=w&3, mh=w>>2),
// 64-row K/V tiles double-buffered (128KB), stage-ahead + single
// __syncthreads per iter; stride-256 thT/phT inputs.
__global__ __launch_bounds__(512, 2) void attn_kernel(
  const unsigned short* __restrict__ thT,
  const unsigned short* __restrict__ phT,
  const unsigned short* __restrict__ gx,
  unsigned short* __restrict__ yT)
{
  __shared__ __align__(16) unsigned char lds[135168]; // 128K KV dbuf + 4K M/L
  const int t = threadIdx.x;
  const int w = t >> 6, l = t & 63, l31 = l & 31, h = l >> 5;
  const int qt = w & 3, mh = w >> 2;
  const int e7 = l31 & 7;
  const int id = blockIdx.x;
  const int b = id & 7;               // XCD-swizzle: one batch per XCD
  const int n0 = (id >> 3) * 128;
  const unsigned short* thB = thT + (size_t)b * N_ * CI_;
  const unsigned short* phB = phT + (size_t)b * N_ * CI_;
  const unsigned short* gxB = gx  + (size_t)b * CI_ * N_;

  // staging source offsets; content swizzle: LDS(row,g) = global(row, g ^ rowbits)
  const int kq = l >> 5, kc = l & 31;
  int koff[4];
#pragma unroll
  for (int i = 0; i < 4; i++) {
    int row = w * 8 + 2 * i + kq;                // K tile row (64 rows)
    koff[i] = row * 256 + ((kc ^ (row & 7)) * 8);
  }
  const int vq = l >> 3, vc = l & 7;
  int voff[4];
#pragma unroll
  for (int i = 0; i < 4; i++) {
    int ci = w * 32 + i * 8 + vq;                // V row (256 ci rows)
    voff[i] = ci * 4096 + ((vc ^ vq) * 8);
  }

#define STAGE(bufv, m0v) do { \
    const unsigned short* kg_ = phB + (size_t)(m0v) * 256; \
    const unsigned short* vg_ = gxB + (m0v); \
    unsigned base_ = (unsigned)(bufv) * 65536u + (unsigned)w * 4096u; \
    _Pragma("unroll") \
    for (int i_ = 0; i_ < 4; i_++) \
      gld16(kg_ + koff[i_], lds + base_ + i_ * 1024); \
    _Pragma("unroll") \
    for (int i_ = 0; i_ < 4; i_++) \
      gld16(vg_ + voff[i_], lds + base_ + 32768u + i_ * 1024); \
  } while (0)

  // Q fragments (B-operand): lane holds Q[n = l31][ci = ks*16 + h*8 + j]
  bf16x8 q[16];
  {
    const unsigned short* qp = thB + (size_t)(n0 + qt * 32 + l31) * CI_ + h * 8;
#pragma unroll
    for (int ks = 0; ks < 16; ks++) q[ks] = *(const bf16x8*)(qp + ks * 16);
  }

  f32x16 acc[8];
#pragma unroll
  for (int i = 0; i < 8; i++)
#pragma unroll
    for (int r = 0; r < 16; r++) acc[i][r] = 0.f;
  float M = -1e30f, L = 0.f;
  const float kS = 0.0625f * 1.44269504f;   // Ci^-0.5 * log2(e)

  STAGE(0, 0);
  __syncthreads();
  int cur = 0;

  for (int tt = 0; tt < 64; tt++) {
    const int m0 = tt * 64;
    if (tt < 63) STAGE(cur ^ 1, m0 + 64);
    const unsigned char* kb = lds + cur * 65536;
    const unsigned char* vb = kb + 32768;

    // S = K * Q over this wave's 32-m half: D[mloc=(r&3)+8*(r>>2)+4h][n=l31]
    f32x16 S;
#pragma unroll
    for (int r = 0; r < 16; r++) S[r] = 0.f;
#pragma unroll
    for (int ks = 0; ks < 16; ks++) {
      bf16x8 kf = *(const bf16x8*)(kb + (mh * 32 + l31) * 512 + ((((ks * 2 + h)) ^ e7) << 4));
      S = mfma32(kf, q[ks], S);
    }

    // online softmax (per-lane col n = l31), log2 domain
    float pm = S[0];
#pragma unroll
    for (int r = 1; r < 16; r++) pm = fmaxf(pm, S[r]);
    pm *= kS;
    pm = fmaxf(pm, __shfl_xor(pm, 32));
    int dfr = __all(pm <= M + 8.0f);          // defer-max (T13)
    if (!dfr) {
      float nm = fmaxf(M, pm);
      float rs = exp2f(M - nm);
      M = nm; L *= rs;
#pragma unroll
      for (int r = 0; r < 16; r++) {
        float rr = __shfl(rs, h * 32 + ((r & 3) + 8 * (r >> 2) + 4 * h));
#pragma unroll
        for (int c = 0; c < 8; c++) acc[c][r] *= rr;
      }
    }
    float p[16];
    float rsum = 0.f;
#pragma unroll
    for (int r = 0; r < 16; r++) {
      p[r] = exp2f(S[r] * kS - M);
      rsum += p[r];
    }
    rsum += __shfl_xor(rsum, 32);
    L += rsum;

    // pack P: pk[qq] covers mloc pair base = 2*(qq&1) + 8*(qq>>1) + 4h
    unsigned pk[8];
#pragma unroll
    for (int qq = 0; qq < 8; qq++)
      pk[qq] = pkbf16(p[2 * qq], p[2 * qq + 1]);

    // PV: A-frag lane l31 = n, k = mloc; words via shfl_xor(32) + select
#pragma unroll
    for (int ks = 0; ks < 2; ks++) {
      unsigned s00 = pk[ks * 4 + 0], s10 = pk[ks * 4 + 2];
      unsigned s01 = pk[ks * 4 + 1], s11 = pk[ks * 4 + 3];
      unsigned own0 = h ? s10 : s00;
      unsigned snd0 = h ? s00 : s10;
      unsigned own1 = h ? s11 : s01;
      unsigned snd1 = h ? s01 : s11;
      unsigned sw0 = (unsigned)__shfl_xor((int)snd0, 32);
      unsigned sw1 = (unsigned)__shfl_xor((int)snd1, 32);
      u32x4 pv;
      pv[0] = h ? sw0 : own0;
      pv[1] = h ? sw1 : own1;
      pv[2] = h ? own0 : sw0;
      pv[3] = h ? own1 : sw1;
      bf16x8 pa = *(bf16x8*)&pv;
      const int gidx = mh * 4 + ks * 2 + h;   // V granule (0..7)
#pragma unroll
      for (int cit = 0; cit < 8; cit++) {
        bf16x8 vf = *(const bf16x8*)(vb + (cit * 32 + l31) * 128 + ((gidx ^ e7) << 4));
        acc[cit] = mfma32(pa, vf, acc[cit]);
      }
    }
    __syncthreads();
    cur ^= 1;
  }

  // ---- pair-merge (qt, mh=0) <- (qt, mh=1) through LDS
  float* MB = (float*)(lds + 131072);          // [2][4][64]
  float* LB = (float*)(lds + 131072 + 2048);   // [2][4][64]
  MB[mh * 256 + qt * 64 + l] = M;
  LB[mh * 256 + qt * 64 + l] = L;
  float* ab = (float*)lds + qt * 8192 + l;     // 32KB region per qt
  if (mh) {
#pragma unroll
    for (int cit = 0; cit < 8; cit++)
#pragma unroll
      for (int r = 0; r < 16; r++)
        ab[(cit * 16 + r) * 64] = acc[cit][r];
  }
  __syncthreads();
  if (!mh) {
    unsigned short* yB = yT + (size_t)b * N_ * CI_;
#pragma unroll
    for (int r = 0; r < 16; r++) {
      int nl = (r & 3) + 8 * (r >> 2) + 4 * h;
      int li = qt * 64 + h * 32 + nl;
      float M1 = MB[li], L1 = LB[li];
      float M2 = MB[256 + li], L2 = LB[256 + li];
      float Mf = fmaxf(M1, M2);
      float s1 = exp2f(M1 - Mf), s2 = exp2f(M2 - Mf);
      float invf = 1.0f / (L1 * s1 + L2 * s2);
      s1 *= invf; s2 *= invf;
      int n = n0 + qt * 32 + nl;
#pragma unroll
      for (int cit = 0; cit < 8; cit++) {
        float v = acc[cit][r] * s1 + ab[(cit * 16 + r) * 64] * s2;
        yB[(size_t)n * CI_ + cit * 32 + l31] = f2b(v);
      }
    }
  }
#undef STAGE
}

// ---------------------------------------------------------------- host
extern "C" void kernel_launch(void* const* d_in, const int* in_sizes, int n_in,
                              void* d_out, int out_size, void* d_ws, size_t ws_size,
                              hipStream_t stream)
{
  const float* x    = (const float*)d_in[0];
  const float* thw  = (const float*)d_in[1];
  const float* thb  = (const float*)d_in[2];
  const float* thg  = (const float*)d_in[3];
  const float* thbb = (const float*)d_in[4];
  const float* thm  = (const float*)d_in[5];
  const float* thv  = (const float*)d_in[6];
  const float* phw  = (const float*)d_in[7];
  const float* phb  = (const float*)d_in[8];
  const float* phg  = (const float*)d_in[9];
  const float* phbb = (const float*)d_in[10];
  const float* phm  = (const float*)d_in[11];
  const float* phv  = (const float*)d_in[12];
  const float* gw   = (const float*)d_in[13];
  const float* gb   = (const float*)d_in[14];
  const float* wzw  = (const float*)d_in[15];
  const float* wzb  = (const float*)d_in[16];
  const float* wzg  = (const float*)d_in[17];
  const float* wzbb = (const float*)d_in[18];
  const float* wzm  = (const float*)d_in[19];
  const float* wzv  = (const float*)d_in[20];

  char* ws = (char*)d_ws;
  unsigned short* xbT  = (unsigned short*)(ws);                    // 32 MB [b][n][512]
  unsigned short* thT  = (unsigned short*)(ws + 33554432ull);      // 16 MB [b][n][256]
  unsigned short* phT  = (unsigned short*)(ws + 50331648ull);      // 16 MB [b][n][256]
  unsigned short* gxb  = (unsigned short*)(ws + 67108864ull);      // 16 MB [b][ci][n]
  unsigned short* yT   = (unsigned short*)(ws + 83886080ull);      // 16 MB [b][n][ci]
  unsigned short* catW = (unsigned short*)(ws + 100663296ull);     // 768x512 bf16
  unsigned short* wzW  = (unsigned short*)(ws + 101449728ull);     // 512x256 bf16
  float* bCat = (float*)(ws + 101711872ull);                       // 768 f32
  float* bWz  = (float*)(ws + 101714944ull);                       // 512 f32

  fold_kernel<<<2053, 256, 0, stream>>>(
      thw, thb, thg, thbb, thm, thv,
      phw, phb, phg, phbb, phm, phv,
      gw, gb, wzw, wzb, wzg, wzbb, wzm, wzv,
      catW, wzW, bCat, bWz);

  transpose_cast<<<dim3(64, 8, 8), 256, 0, stream>>>(x, xbT);

  gemm_proj<<<dim3(32, 6, 8), 256, 0, stream>>>(catW, xbT, bCat, thT, phT, gxb);

  attn_kernel<<<dim3(256), 512, 0, stream>>>(thT, phT, gxb, yT);

  gemm_wz<<<dim3(32, 4, 8), 256, 0, stream>>>(wzW, yT, bWz, x, (float*)d_out);
}